// Round 2
// baseline (72.901 us; speedup 1.0000x reference)
//
#include <hip/hip_runtime.h>
#include <math.h>

#define NS_ITERS 8
#define EPS_N 1e-8f

// index into packed symmetric 4x4 (upper triangle, 10 entries)
__device__ __forceinline__ int sidx(int i, int j) {
    int a = i < j ? i : j;
    int b = i < j ? j : i;
    return a * 4 + b - ((a * (a + 1)) >> 1);
}

// C = A*B for symmetric, commuting 4x4 (result symmetric). All indices
// compile-time after unroll -> pure register code.
__device__ __forceinline__ void symmul4(float* C, const float* A, const float* B) {
#pragma unroll
    for (int i = 0; i < 4; ++i) {
#pragma unroll
        for (int j = i; j < 4; ++j) {
            float s = 0.f;
#pragma unroll
            for (int k = 0; k < 4; ++k)
                s = fmaf(A[sidx(i, k)], B[sidx(k, j)], s);
            C[sidx(i, j)] = s;
        }
    }
}

__global__ __launch_bounds__(256) void orth4x256_kernel(
    const float* __restrict__ x, float* __restrict__ out, int S) {
    const int lane = threadIdx.x & 63;
    const int wave = threadIdx.x >> 6;
    const int s = blockIdx.x * 4 + wave;   // one wave == one sample
    if (s >= S) return;

    // Load A: row m, cols [lane*4, lane*4+4). Consecutive lanes -> contiguous
    // 1 KiB segment per row (fully coalesced float4).
    float4 a[4];
#pragma unroll
    for (int m = 0; m < 4; ++m)
        a[m] = *reinterpret_cast<const float4*>(
            x + ((size_t)m * S + s) * 256 + lane * 4);

    // Per-lane partial Gram entries G[i][j] = sum_d A[i][d]*A[j][d]
    float g[10];
#pragma unroll
    for (int i = 0; i < 4; ++i) {
#pragma unroll
        for (int j = i; j < 4; ++j) {
            g[sidx(i, j)] = a[i].x * a[j].x + a[i].y * a[j].y +
                            a[i].z * a[j].z + a[i].w * a[j].w;
        }
    }

    // Butterfly reduce across the 64-lane wave; every lane ends with totals.
#pragma unroll
    for (int mask = 1; mask < 64; mask <<= 1) {
#pragma unroll
        for (int k = 0; k < 10; ++k)
            g[k] += __shfl_xor(g[k], mask, 64);
    }

    const float trG = g[0] + g[4] + g[7] + g[9];
    const float fro2 =
        g[0] * g[0] + g[4] * g[4] + g[7] * g[7] + g[9] * g[9] +
        2.f * (g[1] * g[1] + g[2] * g[2] + g[3] * g[3] +
               g[5] * g[5] + g[6] * g[6] + g[8] * g[8]);
    const float c = sqrtf(fro2);               // ||G||_F >= ||G||_2
    const bool tiny = !(sqrtf(trG) >= EPS_N);  // reference passthrough case
    const float inv_c = tiny ? 0.f : (1.f / c);

    // Coupled Newton-Schulz: Y0 = G/c (eigs in (0,1]), Z0 = I.
    // Y -> (G/c)^{1/2}, Z -> (G/c)^{-1/2}. All iterates symmetric & commute.
    float Y[10], Z[10];
#pragma unroll
    for (int k = 0; k < 10; ++k) { Y[k] = g[k] * inv_c; Z[k] = 0.f; }
    Z[0] = Z[4] = Z[7] = Z[9] = 1.f;

#pragma unroll
    for (int it = 0; it < NS_ITERS; ++it) {
        float P[10], T[10], Yn[10], Zn[10];
        symmul4(P, Z, Y);                      // P = Z*Y
#pragma unroll
        for (int k = 0; k < 10; ++k) T[k] = -0.5f * P[k];
        T[0] += 1.5f; T[4] += 1.5f; T[7] += 1.5f; T[9] += 1.5f;  // T=(3I-P)/2
        symmul4(Yn, Y, T);
        symmul4(Zn, Z, T);
#pragma unroll
        for (int k = 0; k < 10; ++k) { Y[k] = Yn[k]; Z[k] = Zn[k]; }
    }

    // B = G^{-1/2} = Z / sqrt(c); passthrough -> identity.
    const float rs = rsqrtf(c);
    const float idm[10] = {1.f, 0.f, 0.f, 0.f, 1.f, 0.f, 0.f, 1.f, 0.f, 1.f};
    float B[10];
#pragma unroll
    for (int k = 0; k < 10; ++k) B[k] = tiny ? idm[k] : (Z[k] * rs);

    // out = B * A  (4x4 times 4x256), coalesced float4 stores
#pragma unroll
    for (int m = 0; m < 4; ++m) {
        float4 o;
        o.x = B[sidx(m, 0)] * a[0].x + B[sidx(m, 1)] * a[1].x +
              B[sidx(m, 2)] * a[2].x + B[sidx(m, 3)] * a[3].x;
        o.y = B[sidx(m, 0)] * a[0].y + B[sidx(m, 1)] * a[1].y +
              B[sidx(m, 2)] * a[2].y + B[sidx(m, 3)] * a[3].y;
        o.z = B[sidx(m, 0)] * a[0].z + B[sidx(m, 1)] * a[1].z +
              B[sidx(m, 2)] * a[2].z + B[sidx(m, 3)] * a[3].z;
        o.w = B[sidx(m, 0)] * a[0].w + B[sidx(m, 1)] * a[1].w +
              B[sidx(m, 2)] * a[2].w + B[sidx(m, 3)] * a[3].w;
        *reinterpret_cast<float4*>(out + ((size_t)m * S + s) * 256 + lane * 4) = o;
    }
}

extern "C" void kernel_launch(void* const* d_in, const int* in_sizes, int n_in,
                              void* d_out, int out_size, void* d_ws, size_t ws_size,
                              hipStream_t stream) {
    const float* x = (const float*)d_in[0];
    float* out = (float*)d_out;
    const int S = in_sizes[0] / (4 * 256);   // n_samples
    const int blocks = (S + 3) / 4;          // 4 waves/block, 1 sample/wave
    hipLaunchKernelGGL(orth4x256_kernel, dim3(blocks), dim3(256), 0, stream,
                       x, out, S);
}

// Round 3
// 45.402 us; speedup vs baseline: 1.6057x; 1.6057x over previous
//
#include <hip/hip_runtime.h>
#include <math.h>

#define NS_ITERS 6
#define EPS_N 1e-8f

// index into packed symmetric 4x4 (upper triangle, 10 entries)
__device__ __forceinline__ int sidx(int i, int j) {
    int a = i < j ? i : j;
    int b = i < j ? j : i;
    return a * 4 + b - ((a * (a + 1)) >> 1);
}

// C = A*B for symmetric, commuting 4x4 (result symmetric, 10 entries).
__device__ __forceinline__ void symmul4(float* C, const float* A, const float* B) {
#pragma unroll
    for (int i = 0; i < 4; ++i) {
#pragma unroll
        for (int j = i; j < 4; ++j) {
            float s = 0.f;
#pragma unroll
            for (int k = 0; k < 4; ++k)
                s = fmaf(A[sidx(i, k)], B[sidx(k, j)], s);
            C[sidx(i, j)] = s;
        }
    }
}

// 4 samples per wave, 16 lanes per sample. Each lane holds 4 rows x 16 cols
// of its sample (16 float4). NS redundancy drops 64x -> 16x.
__global__ __launch_bounds__(256) void orth4x256_v2(
    const float* __restrict__ x, float* __restrict__ out, int S) {
    const int lane = threadIdx.x & 63;
    const int wave = threadIdx.x >> 6;
    const int grp  = lane >> 4;          // sample within the wave (0..3)
    const int l    = lane & 15;          // lane within the 16-lane group
    const int s = blockIdx.x * 16 + wave * 4 + grp;
    if (s >= S) return;

    // a[m][q]: row m, cols [q*64 + l*4, +4). Per load inst the wave touches
    // four contiguous 256B segments (one per sample) -> fully coalesced.
    float4 a[4][4];
#pragma unroll
    for (int m = 0; m < 4; ++m) {
        const float* rp = x + ((size_t)m * S + s) * 256 + l * 4;
#pragma unroll
        for (int q = 0; q < 4; ++q)
            a[m][q] = *reinterpret_cast<const float4*>(rp + q * 64);
    }

    // Per-lane partial Gram: G[i][j] = sum_d A[i][d]*A[j][d]
    float g[10];
#pragma unroll
    for (int i = 0; i < 4; ++i) {
#pragma unroll
        for (int j = i; j < 4; ++j) {
            float t = 0.f;
#pragma unroll
            for (int q = 0; q < 4; ++q) {
                t = fmaf(a[i][q].x, a[j][q].x, t);
                t = fmaf(a[i][q].y, a[j][q].y, t);
                t = fmaf(a[i][q].z, a[j][q].z, t);
                t = fmaf(a[i][q].w, a[j][q].w, t);
            }
            g[sidx(i, j)] = t;
        }
    }

    // Butterfly reduce across the 16-lane group (xor masks stay in-group).
#pragma unroll
    for (int mask = 1; mask < 16; mask <<= 1) {
#pragma unroll
        for (int k = 0; k < 10; ++k)
            g[k] += __shfl_xor(g[k], mask, 64);
    }

    const float trG = g[0] + g[4] + g[7] + g[9];
    const float fro2 =
        g[0] * g[0] + g[4] * g[4] + g[7] * g[7] + g[9] * g[9] +
        2.f * (g[1] * g[1] + g[2] * g[2] + g[3] * g[3] +
               g[5] * g[5] + g[6] * g[6] + g[8] * g[8]);
    const float c = sqrtf(fro2);               // ||G||_F >= ||G||_2
    const bool tiny = !(sqrtf(trG) >= EPS_N);  // reference passthrough case
    const float inv_c = tiny ? 0.f : (1.f / c);

    // Coupled Newton-Schulz: Y0 = G/c (eigs in (0,1]), Z0 = I.
    // Y -> (G/c)^{1/2}, Z -> (G/c)^{-1/2}; iterates symmetric & commute.
    float Y[10], Z[10];
#pragma unroll
    for (int k = 0; k < 10; ++k) { Y[k] = g[k] * inv_c; Z[k] = 0.f; }
    Z[0] = Z[4] = Z[7] = Z[9] = 1.f;

#pragma unroll
    for (int it = 0; it < NS_ITERS; ++it) {
        float P[10], T[10], Yn[10], Zn[10];
        symmul4(P, Z, Y);                      // P = Z*Y
#pragma unroll
        for (int k = 0; k < 10; ++k) T[k] = -0.5f * P[k];
        T[0] += 1.5f; T[4] += 1.5f; T[7] += 1.5f; T[9] += 1.5f;  // (3I-P)/2
        symmul4(Yn, Y, T);
        symmul4(Zn, Z, T);
#pragma unroll
        for (int k = 0; k < 10; ++k) { Y[k] = Yn[k]; Z[k] = Zn[k]; }
    }

    // B = G^{-1/2} = Z / sqrt(c); passthrough -> identity.
    const float rs = rsqrtf(c);
    const float idm[10] = {1.f, 0.f, 0.f, 0.f, 1.f, 0.f, 0.f, 1.f, 0.f, 1.f};
    float B[10];
#pragma unroll
    for (int k = 0; k < 10; ++k) B[k] = tiny ? idm[k] : (Z[k] * rs);

    // out = B * A (4x4 times 4x256), coalesced float4 stores
#pragma unroll
    for (int m = 0; m < 4; ++m) {
        float* wp = out + ((size_t)m * S + s) * 256 + l * 4;
#pragma unroll
        for (int q = 0; q < 4; ++q) {
            float4 o;
            o.x = B[sidx(m, 0)] * a[0][q].x + B[sidx(m, 1)] * a[1][q].x +
                  B[sidx(m, 2)] * a[2][q].x + B[sidx(m, 3)] * a[3][q].x;
            o.y = B[sidx(m, 0)] * a[0][q].y + B[sidx(m, 1)] * a[1][q].y +
                  B[sidx(m, 2)] * a[2][q].y + B[sidx(m, 3)] * a[3][q].y;
            o.z = B[sidx(m, 0)] * a[0][q].z + B[sidx(m, 1)] * a[1][q].z +
                  B[sidx(m, 2)] * a[2][q].z + B[sidx(m, 3)] * a[3][q].z;
            o.w = B[sidx(m, 0)] * a[0][q].w + B[sidx(m, 1)] * a[1][q].w +
                  B[sidx(m, 2)] * a[2][q].w + B[sidx(m, 3)] * a[3][q].w;
            *reinterpret_cast<float4*>(wp + q * 64) = o;
        }
    }
}

extern "C" void kernel_launch(void* const* d_in, const int* in_sizes, int n_in,
                              void* d_out, int out_size, void* d_ws, size_t ws_size,
                              hipStream_t stream) {
    const float* x = (const float*)d_in[0];
    float* out = (float*)d_out;
    const int S = in_sizes[0] / (4 * 256);   // n_samples
    const int blocks = (S + 15) / 16;        // 16 samples/block (4 waves x 4)
    hipLaunchKernelGGL(orth4x256_v2, dim3(blocks), dim3(256), 0, stream,
                       x, out, S);
}

// Round 5
// 45.230 us; speedup vs baseline: 1.6118x; 1.0038x over previous
//
#include <hip/hip_runtime.h>
#include <math.h>

#define NS_ITERS 6
#define EPS_N 1e-8f

typedef float f32x4 __attribute__((ext_vector_type(4)));  // native vec for nt-store

// index into packed symmetric 4x4 (upper triangle, 10 entries)
__device__ __forceinline__ int sidx(int i, int j) {
    int a = i < j ? i : j;
    int b = i < j ? j : i;
    return a * 4 + b - ((a * (a + 1)) >> 1);
}

// C = A*B for symmetric, commuting 4x4 (result symmetric, 10 entries).
__device__ __forceinline__ void symmul4(float* C, const float* A, const float* B) {
#pragma unroll
    for (int i = 0; i < 4; ++i) {
#pragma unroll
        for (int j = i; j < 4; ++j) {
            float s = 0.f;
#pragma unroll
            for (int k = 0; k < 4; ++k)
                s = fmaf(A[sidx(i, k)], B[sidx(k, j)], s);
            C[sidx(i, j)] = s;
        }
    }
}

// 4 samples per wave, 16 lanes per sample. Each lane holds 4 rows x 16 cols
// of its sample (16 float4). NS redundancy 16x. Output via non-temporal
// stores so the write stream doesn't evict the L3-resident input.
__global__ __launch_bounds__(256) void orth4x256_v3(
    const float* __restrict__ x, float* __restrict__ out, int S) {
    const int lane = threadIdx.x & 63;
    const int wave = threadIdx.x >> 6;
    const int grp  = lane >> 4;          // sample within the wave (0..3)
    const int l    = lane & 15;          // lane within the 16-lane group
    const int s = blockIdx.x * 16 + wave * 4 + grp;
    if (s >= S) return;

    // a[m][q]: row m, cols [q*64 + l*4, +4). Per load inst the wave touches
    // four contiguous 256B segments (one per sample) -> fully coalesced.
    f32x4 a[4][4];
#pragma unroll
    for (int m = 0; m < 4; ++m) {
        const float* rp = x + ((size_t)m * S + s) * 256 + l * 4;
#pragma unroll
        for (int q = 0; q < 4; ++q)
            a[m][q] = *reinterpret_cast<const f32x4*>(rp + q * 64);
    }

    // Per-lane partial Gram: G[i][j] = sum_d A[i][d]*A[j][d]
    float g[10];
#pragma unroll
    for (int i = 0; i < 4; ++i) {
#pragma unroll
        for (int j = i; j < 4; ++j) {
            float t = 0.f;
#pragma unroll
            for (int q = 0; q < 4; ++q) {
                t = fmaf(a[i][q].x, a[j][q].x, t);
                t = fmaf(a[i][q].y, a[j][q].y, t);
                t = fmaf(a[i][q].z, a[j][q].z, t);
                t = fmaf(a[i][q].w, a[j][q].w, t);
            }
            g[sidx(i, j)] = t;
        }
    }

    // Butterfly reduce across the 16-lane group (xor masks stay in-group).
#pragma unroll
    for (int mask = 1; mask < 16; mask <<= 1) {
#pragma unroll
        for (int k = 0; k < 10; ++k)
            g[k] += __shfl_xor(g[k], mask, 64);
    }

    const float trG = g[0] + g[4] + g[7] + g[9];
    const float fro2 =
        g[0] * g[0] + g[4] * g[4] + g[7] * g[7] + g[9] * g[9] +
        2.f * (g[1] * g[1] + g[2] * g[2] + g[3] * g[3] +
               g[5] * g[5] + g[6] * g[6] + g[8] * g[8]);
    const float c = sqrtf(fro2);               // ||G||_F >= ||G||_2
    const bool tiny = !(sqrtf(trG) >= EPS_N);  // reference passthrough case
    const float inv_c = tiny ? 0.f : (1.f / c);

    // Coupled Newton-Schulz: Y0 = G/c (eigs in (0,1]), Z0 = I.
    // Y -> (G/c)^{1/2}, Z -> (G/c)^{-1/2}; iterates symmetric & commute.
    float Y[10], Z[10];
#pragma unroll
    for (int k = 0; k < 10; ++k) { Y[k] = g[k] * inv_c; Z[k] = 0.f; }
    Z[0] = Z[4] = Z[7] = Z[9] = 1.f;

#pragma unroll
    for (int it = 0; it < NS_ITERS; ++it) {
        float P[10], T[10], Yn[10], Zn[10];
        symmul4(P, Z, Y);                      // P = Z*Y
#pragma unroll
        for (int k = 0; k < 10; ++k) T[k] = -0.5f * P[k];
        T[0] += 1.5f; T[4] += 1.5f; T[7] += 1.5f; T[9] += 1.5f;  // (3I-P)/2
        symmul4(Yn, Y, T);
        symmul4(Zn, Z, T);
#pragma unroll
        for (int k = 0; k < 10; ++k) { Y[k] = Yn[k]; Z[k] = Zn[k]; }
    }

    // B = G^{-1/2} = Z / sqrt(c); passthrough -> identity.
    const float rs = rsqrtf(c);
    const float idm[10] = {1.f, 0.f, 0.f, 0.f, 1.f, 0.f, 0.f, 1.f, 0.f, 1.f};
    float B[10];
#pragma unroll
    for (int k = 0; k < 10; ++k) B[k] = tiny ? idm[k] : (Z[k] * rs);

    // out = B * A (4x4 times 4x256); non-temporal coalesced float4 stores.
#pragma unroll
    for (int m = 0; m < 4; ++m) {
        float* wp = out + ((size_t)m * S + s) * 256 + l * 4;
#pragma unroll
        for (int q = 0; q < 4; ++q) {
            f32x4 o;
            o.x = B[sidx(m, 0)] * a[0][q].x + B[sidx(m, 1)] * a[1][q].x +
                  B[sidx(m, 2)] * a[2][q].x + B[sidx(m, 3)] * a[3][q].x;
            o.y = B[sidx(m, 0)] * a[0][q].y + B[sidx(m, 1)] * a[1][q].y +
                  B[sidx(m, 2)] * a[2][q].y + B[sidx(m, 3)] * a[3][q].y;
            o.z = B[sidx(m, 0)] * a[0][q].z + B[sidx(m, 1)] * a[1][q].z +
                  B[sidx(m, 2)] * a[2][q].z + B[sidx(m, 3)] * a[3][q].z;
            o.w = B[sidx(m, 0)] * a[0][q].w + B[sidx(m, 1)] * a[1][q].w +
                  B[sidx(m, 2)] * a[2][q].w + B[sidx(m, 3)] * a[3][q].w;
            __builtin_nontemporal_store(o, reinterpret_cast<f32x4*>(wp + q * 64));
        }
    }
}

extern "C" void kernel_launch(void* const* d_in, const int* in_sizes, int n_in,
                              void* d_out, int out_size, void* d_ws, size_t ws_size,
                              hipStream_t stream) {
    const float* x = (const float*)d_in[0];
    float* out = (float*)d_out;
    const int S = in_sizes[0] / (4 * 256);   // n_samples
    const int blocks = (S + 15) / 16;        // 16 samples/block (4 waves x 4)
    hipLaunchKernelGGL(orth4x256_v3, dim3(blocks), dim3(256), 0, stream,
                       x, out, S);
}